// Round 1
// baseline (2808.348 us; speedup 1.0000x reference)
//
#include <hip/hip_runtime.h>

typedef __bf16 bf16_t;
typedef bf16_t bf16x8 __attribute__((ext_vector_type(8)));
typedef float  f32x4  __attribute__((ext_vector_type(4)));

#define MFMA16(A, B, C) __builtin_amdgcn_mfma_f32_16x16x32_bf16((A), (B), (C), 0, 0, 0)

static constexpr int KEXT    = 288;   // 256 h | 3 x | 1 ones(bias) | 28 zero pad
static constexpr int TSTEPS  = 128;
static constexpr int TILE_B  = 32;
static constexpr int HSTRIDE = 296;   // hext LDS row stride (bf16): 592B -> 2-way (free) bank pattern
static constexpr int ZSTRIDE = 136;

// ws layout (bf16 elements):
static constexpr int WALL_OFF = 0;                   // [1152][288]  gates(1024)+Wo1(128) rows
static constexpr int W2E_OFF  = 1152 * 288;          // [512][288]   encoder layer2 (+b2 col)
static constexpr int WO2E_OFF = W2E_OFF + 512 * 288; // [16][128]    Wo2 padded to 16 rows
static constexpr int WS_ELEMS = WO2E_OFF + 16 * 128;

// ---------------- weight prep (runs every launch; ws is re-poisoned) ----------------
__global__ __launch_bounds__(256) void prep_kernel(
    const float* __restrict__ W2,  const float* __restrict__ b2,
    const float* __restrict__ Wih, const float* __restrict__ Whh,
    const float* __restrict__ bih, const float* __restrict__ bhh,
    const float* __restrict__ Wo1, const float* __restrict__ bo1,
    const float* __restrict__ Wo2, bf16_t* __restrict__ ws)
{
    int idx = blockIdx.x * 256 + threadIdx.x;
    if (idx < 1152 * 288) {
        int r = idx / 288, k = idx - r * 288;
        float v = 0.f;
        if (r < 1024) {                       // gate rows: i(0..255) f g o
            if (k < 256)       v = Whh[r * 256 + k];
            else if (k < 259)  v = Wih[r * 3 + (k - 256)];
            else if (k == 259) v = bih[r] + bhh[r];
        } else {                              // Wo1 rows
            int q = r - 1024;
            if (k < 256)       v = Wo1[q * 256 + k];
            else if (k == 259) v = bo1[q];
        }
        ws[WALL_OFF + idx] = (bf16_t)v;
    } else if (idx < W2E_OFF + 512 * 288) {
        int j = idx - W2E_OFF;
        int u = j / 288, k = j - u * 288;
        float v = 0.f;
        if (k < 256)       v = W2[u * 256 + k];
        else if (k == 259) v = b2[u];
        ws[idx] = (bf16_t)v;
    } else if (idx < WS_ELEMS) {
        int j = idx - WO2E_OFF;
        int d = j >> 7, q = j & 127;
        ws[idx] = (bf16_t)((d < 3) ? Wo2[d * 128 + q] : 0.f);
    }
}

__device__ __forceinline__ float sigm(float x) { return 1.f / (1.f + __expf(-x)); }
__device__ __forceinline__ float tanh_f(float x) {
    float a = fminf(fmaxf(x, -15.f), 15.f);
    float e = __expf(2.f * a);
    return (e - 1.f) / (e + 1.f);
}

// ---------------- main persistent kernel: 1 block = 32 batch rows, all 128 steps ----------------
__global__ __launch_bounds__(512, 2) void lstm_main(
    const float* __restrict__ meta, const float* __restrict__ W1,
    const float* __restrict__ b1,   const float* __restrict__ bo2,
    const bf16_t* __restrict__ ws,  float* __restrict__ out)
{
    __shared__ __align__(16) bf16_t hext[TILE_B][HSTRIDE]; // h(256) | x(3) | 1.0 | zeros
    __shared__ __align__(16) bf16_t zbuf[TILE_B][ZSTRIDE]; // relu(h@Wo1^T+bo1), 128 wide

    const int tid  = threadIdx.x;
    const int wave = tid >> 6;       // 0..7
    const int lane = tid & 63;
    const int l15  = lane & 15;
    const int quad = lane >> 4;      // 0..3
    const int b0   = blockIdx.x * TILE_B;

    const bf16_t* Wall = ws + WALL_OFF;
    const bf16_t* W2e  = ws + W2E_OFF;
    const bf16_t* Wo2e = ws + WO2E_OFF;

    // ---- init extension columns + encoder layer 1 (VALU fp32, K=7) ----
    if (tid < TILE_B) {
        int b = tid;
        #pragma unroll
        for (int d = 0; d < 32; ++d) {
            float v = 0.f;
            if (d < 3)       v = meta[(size_t)(b0 + b) * 7 + d];  // x0 = metadata[:, :3]
            else if (d == 3) v = 1.f;                              // ones column (bias)
            hext[b][256 + d] = (bf16_t)v;
        }
    }
    {
        int b  = tid & 31;
        int jb = (tid >> 5) * 16;
        float m[7];
        #pragma unroll
        for (int k = 0; k < 7; ++k) m[k] = meta[(size_t)(b0 + b) * 7 + k];
        #pragma unroll
        for (int jj = 0; jj < 16; ++jj) {
            int j = jb + jj;
            float acc = b1[j];
            #pragma unroll
            for (int k = 0; k < 7; ++k) acc += W1[j * 7 + k] * m[k];
            hext[b][j] = (bf16_t)fmaxf(acc, 0.f);   // enc1, staged bf16
        }
    }
    __syncthreads();

    // ---- encoder layer 2 via MFMA: wave w owns u-tiles {2w,2w+1} (h0) and {16+2w,16+2w+1} (c0) ----
    float creg[2][2][4];
    {
        f32x4 eacc[4][2];
        const f32x4 z4 = {0.f, 0.f, 0.f, 0.f};
        #pragma unroll
        for (int m = 0; m < 4; ++m) { eacc[m][0] = z4; eacc[m][1] = z4; }
        int erows[4] = {32 * wave, 32 * wave + 16, 256 + 32 * wave, 256 + 32 * wave + 16};
        for (int kk = 0; kk < 9; ++kk) {
            int ko = 32 * kk + 8 * quad;
            bf16x8 bf0 = *reinterpret_cast<const bf16x8*>(&hext[l15][ko]);
            bf16x8 bf1 = *reinterpret_cast<const bf16x8*>(&hext[16 + l15][ko]);
            #pragma unroll
            for (int m = 0; m < 4; ++m) {
                bf16x8 af = *reinterpret_cast<const bf16x8*>(&W2e[(size_t)(erows[m] + l15) * KEXT + ko]);
                eacc[m][0] = MFMA16(af, bf0, eacc[m][0]);
                eacc[m][1] = MFMA16(af, bf1, eacc[m][1]);
            }
        }
        __syncthreads();   // all enc1 reads done before overwriting hext with h0
        #pragma unroll
        for (int m = 0; m < 2; ++m)
            #pragma unroll
            for (int nt = 0; nt < 2; ++nt)
                #pragma unroll
                for (int r = 0; r < 4; ++r) {
                    int j = 32 * wave + 16 * m + 4 * quad + r;
                    int b = 16 * nt + l15;
                    hext[b][j]      = (bf16_t)fmaxf(eacc[m][nt][r], 0.f);      // h0
                    creg[m][nt][r]  = fmaxf(eacc[2 + m][nt][r], 0.f);          // c0 (lane-matched)
                }
        __syncthreads();
    }

    // ---- gate row bases for this wave: dims [32w, 32w+32) across i,f,g,o ----
    int mrows[8];
    {
        int w32 = 32 * wave;
        mrows[0] = w32;        mrows[1] = w32 + 16;
        mrows[2] = 256 + w32;  mrows[3] = 256 + w32 + 16;
        mrows[4] = 512 + w32;  mrows[5] = 512 + w32 + 16;
        mrows[6] = 768 + w32;  mrows[7] = 768 + w32 + 16;
    }
    const int zrow = 1024 + 16 * wave;
    const f32x4 zero4 = {0.f, 0.f, 0.f, 0.f};

    for (int t = 0; t < TSTEPS; ++t) {
        // -- phase 1: gates = [h_t | x_t | 1] @ Wall_gates^T  (bias+Wih fused via K-extension) --
        f32x4 acc[8][2];
        #pragma unroll
        for (int m = 0; m < 8; ++m) { acc[m][0] = zero4; acc[m][1] = zero4; }
        for (int kk = 0; kk < 9; ++kk) {
            int ko = 32 * kk + 8 * quad;
            bf16x8 bf0 = *reinterpret_cast<const bf16x8*>(&hext[l15][ko]);
            bf16x8 bf1 = *reinterpret_cast<const bf16x8*>(&hext[16 + l15][ko]);
            #pragma unroll
            for (int m = 0; m < 8; ++m) {
                bf16x8 af = *reinterpret_cast<const bf16x8*>(&Wall[(size_t)(mrows[m] + l15) * KEXT + ko]);
                acc[m][0] = MFMA16(af, bf0, acc[m][0]);
                acc[m][1] = MFMA16(af, bf1, acc[m][1]);
            }
        }
        __syncthreads();   // (a) all hext reads complete before h is overwritten

        // -- phase 2: LSTM cell update; c stays in fp32 regs, h_{t+1} -> hext bf16 --
        #pragma unroll
        for (int dtl = 0; dtl < 2; ++dtl)
            #pragma unroll
            for (int nt = 0; nt < 2; ++nt)
                #pragma unroll
                for (int r = 0; r < 4; ++r) {
                    float iv = acc[0 + dtl][nt][r];
                    float fv = acc[2 + dtl][nt][r];
                    float gv = acc[4 + dtl][nt][r];
                    float ov = acc[6 + dtl][nt][r];
                    float c  = sigm(fv) * creg[dtl][nt][r] + sigm(iv) * tanh_f(gv);
                    creg[dtl][nt][r] = c;
                    float h  = sigm(ov) * tanh_f(c);
                    int j = 32 * wave + 16 * dtl + 4 * quad + r;
                    hext[16 * nt + l15][j] = (bf16_t)h;
                }
        __syncthreads();   // (b) h_{t+1} visible

        // -- phase 3: z = relu(h_{t+1} @ Wo1^T + bo1)  (Wo1 rows have zeros at x cols, bo1 at ones col) --
        {
            f32x4 zacc[2] = {zero4, zero4};
            for (int kk = 0; kk < 9; ++kk) {
                int ko = 32 * kk + 8 * quad;
                bf16x8 bf0 = *reinterpret_cast<const bf16x8*>(&hext[l15][ko]);
                bf16x8 bf1 = *reinterpret_cast<const bf16x8*>(&hext[16 + l15][ko]);
                bf16x8 af  = *reinterpret_cast<const bf16x8*>(&Wall[(size_t)(zrow + l15) * KEXT + ko]);
                zacc[0] = MFMA16(af, bf0, zacc[0]);
                zacc[1] = MFMA16(af, bf1, zacc[1]);
            }
            #pragma unroll
            for (int nt = 0; nt < 2; ++nt)
                #pragma unroll
                for (int r = 0; r < 4; ++r) {
                    int q = 16 * wave + 4 * quad + r;
                    zbuf[16 * nt + l15][q] = (bf16_t)fmaxf(zacc[nt][r], 0.f);
                }
        }
        __syncthreads();   // (c) zbuf complete

        // -- phase 4 (wave 0): y = z @ Wo2^T + bo2; emit y_t and x_{t+1}=y_t --
        if (wave == 0) {
            f32x4 ya[2] = {zero4, zero4};
            for (int kk = 0; kk < 4; ++kk) {
                int ko = 32 * kk + 8 * quad;
                bf16x8 af  = *reinterpret_cast<const bf16x8*>(&Wo2e[(size_t)l15 * 128 + ko]);
                bf16x8 bz0 = *reinterpret_cast<const bf16x8*>(&zbuf[l15][ko]);
                bf16x8 bz1 = *reinterpret_cast<const bf16x8*>(&zbuf[16 + l15][ko]);
                ya[0] = MFMA16(af, bz0, ya[0]);
                ya[1] = MFMA16(af, bz1, ya[1]);
            }
            if (quad == 0) {   // rows d = reg; only d<3 are real
                #pragma unroll
                for (int nt = 0; nt < 2; ++nt)
                    #pragma unroll
                    for (int r = 0; r < 3; ++r) {
                        int b = 16 * nt + l15;
                        float yv = ya[nt][r] + bo2[r];
                        out[((size_t)(b0 + b) * TSTEPS + t) * 3 + r] = yv;
                        hext[b][256 + r] = (bf16_t)yv;    // x_{t+1}
                    }
            }
        }
        __syncthreads();   // (d) x_{t+1} visible for next step's gate MFMA
    }
}

extern "C" void kernel_launch(void* const* d_in, const int* in_sizes, int n_in,
                              void* d_out, int out_size, void* d_ws, size_t ws_size,
                              hipStream_t stream)
{
    const float* meta = (const float*)d_in[0];
    // d_in[1] = target_seq_len (always 128)
    const float* W1   = (const float*)d_in[2];
    const float* b1   = (const float*)d_in[3];
    const float* W2   = (const float*)d_in[4];
    const float* b2   = (const float*)d_in[5];
    const float* Wih  = (const float*)d_in[6];
    const float* Whh  = (const float*)d_in[7];
    const float* bih  = (const float*)d_in[8];
    const float* bhh  = (const float*)d_in[9];
    const float* Wo1  = (const float*)d_in[10];
    const float* bo1  = (const float*)d_in[11];
    const float* Wo2  = (const float*)d_in[12];
    const float* bo2  = (const float*)d_in[13];
    bf16_t* ws  = (bf16_t*)d_ws;
    float*  out = (float*)d_out;

    prep_kernel<<<dim3((WS_ELEMS + 255) / 256), dim3(256), 0, stream>>>(
        W2, b2, Wih, Whh, bih, bhh, Wo1, bo1, Wo2, ws);
    lstm_main<<<dim3(4096 / TILE_B), dim3(512), 0, stream>>>(
        meta, W1, b1, bo2, ws, out);
}